// Round 11
// baseline (510.165 us; speedup 1.0000x reference)
//
#include <hip/hip_runtime.h>

// Neurcomp / SIREN MLP inference — round 11: 16 points/wave.
// r6-r10 all sit at ~19% occupancy (~6 waves/CU) regardless of LDS/block
// -> supply-limited: 6250 waves / 256 CU = 24/CU, each ~T/4 long. The
// wall is the per-wave serial latency chain (vmcnt weight fetch + lgkm
// write->read) with too few waves to hide it. Fix: halve the M-tile to
// 16 pts/wave -> 12500 waves (2x supply), 8.7 KB LDS/wave, per-wave
// chain halved. VALU/MFMA totals unchanged; L2 weight traffic doubles
// (14 TB/s equiv, under the 34.5 TB/s ceiling). fp16 3-term split
// numerics of r10 kept verbatim (absmax 4.88e-4 = 1 ulp).
// Layouts (verified): A[m=lane&15][k=(lane>>4)*8+j],
// B[k=(lane>>4)*8+j][n=lane&15], C/D col=lane&15 row=(lane>>4)*4+reg.

typedef unsigned int u32;
typedef _Float16 h8v __attribute__((ext_vector_type(8)));  // 8 fp16
typedef float f4v __attribute__((ext_vector_type(4)));
typedef u32   u4v __attribute__((ext_vector_type(4)));
typedef u32   u2v __attribute__((ext_vector_type(2)));

constexpr float OMEGA = 30.0f;
constexpr float INV2PI = 0.15915494309189535f;
constexpr float KIN = 2.44140625e-4f;   // 1/4096
constexpr int HID = 128, NRES = 7, BT = 64, PPW = 16;  // points per wave
constexpr int RSTR = 136;               // u16 per plane row (17 x 16B)
constexpr int FRAG_ELEMS = 14 * 16384;  // f16 elems per hi/lo ws array

__device__ __forceinline__ float sin_om(float z) {     // sin(OMEGA*z)
    float r = z * (OMEGA * INV2PI);
    r = r - floorf(r);
    return __builtin_amdgcn_sinf(r);
}
__device__ __forceinline__ float sin_q(float z) {      // sin(OMEGA*z/256)
    float r = z * (OMEGA * INV2PI / 256.0f);
    r = r - floorf(r);
    return __builtin_amdgcn_sinf(r);
}

__device__ __forceinline__ f4v mfmaf(h8v a, h8v b, f4v c) {
    return __builtin_amdgcn_mfma_f32_16x16x32_f16(a, b, c, 0, 0, 0);
}

__device__ __forceinline__ u32 pk2(_Float16 a, _Float16 b) {
    u32 ua = (u32)__builtin_bit_cast(unsigned short, a);
    u32 ub = (u32)__builtin_bit_cast(unsigned short, b);
    return ua | (ub << 16);
}

// split 4 consecutive-feature fp32 values into hi/lo fp16 planes
// (lo pre-scaled x4096), one ds_write_b64 per plane.
__device__ __forceinline__ void plane_store4(unsigned short* ph,
                                             unsigned short* pl,
                                             int a, f4v v) {
    _Float16 h0 = (_Float16)v.x, h1 = (_Float16)v.y,
             h2 = (_Float16)v.z, h3 = (_Float16)v.w;
    u2v hv; hv.x = pk2(h0, h1); hv.y = pk2(h2, h3);
    _Float16 l0 = (_Float16)((v.x - (float)h0) * 4096.f);
    _Float16 l1 = (_Float16)((v.y - (float)h1) * 4096.f);
    _Float16 l2 = (_Float16)((v.z - (float)h2) * 4096.f);
    _Float16 l3 = (_Float16)((v.w - (float)h3) * 4096.f);
    u2v lv; lv.x = pk2(l0, l1); lv.y = pk2(l2, l3);
    *reinterpret_cast<u2v*>(ph + a) = hv;
    *reinterpret_cast<u2v*>(pl + a) = lv;
}

// ---- repetition lists ----
#define LMT8(M) M(0) M(1) M(2) M(3) M(4) M(5) M(6) M(7)
#define LF32(M) \
  M(0,0) M(0,1) M(0,2) M(0,3) M(1,0) M(1,1) M(1,2) M(1,3) \
  M(2,0) M(2,1) M(2,2) M(2,3) M(3,0) M(3,1) M(3,2) M(3,3) \
  M(4,0) M(4,1) M(4,2) M(4,3) M(5,0) M(5,1) M(5,2) M(5,3) \
  M(6,0) M(6,1) M(6,2) M(6,3) M(7,0) M(7,1) M(7,2) M(7,3)
#define LT8X(M) \
  M(0, H_0_0,H_0_1,H_0_2,H_0_3) \
  M(1, H_1_0,H_1_1,H_1_2,H_1_3) \
  M(2, H_2_0,H_2_1,H_2_2,H_2_3) \
  M(3, H_3_0,H_3_1,H_3_2,H_3_3) \
  M(4, H_4_0,H_4_1,H_4_2,H_4_3) \
  M(5, H_5_0,H_5_1,H_5_2,H_5_3) \
  M(6, H_6_0,H_6_1,H_6_2,H_6_3) \
  M(7, H_7_0,H_7_1,H_7_2,H_7_3)

// ---- weight prep: fp32 W -> x256-scaled hi/lo fp16 A-frags in d_ws ----
__global__ void prep_kernel(const float* __restrict__ rw1,
                            const float* __restrict__ rw2,
                            unsigned short* __restrict__ wsHi,
                            unsigned short* __restrict__ wsLo) {
    int id = blockIdx.x * 256 + threadIdx.x;      // 0 .. 28671
    int lane = id & 63, kc = (id >> 6) & 3, t = (id >> 8) & 7, L = id >> 11;
    int i = L >> 1;
    bool isW1 = ((L & 1) == 0);
    const float* W = (isW1 ? rw1 : rw2) + i * HID * HID;
    float sc = ((isW1 && i > 0) ? 0.5f : 1.0f) * 256.0f;  // fold wgt1, x256
    int m = t * 16 + (lane & 15);                  // A row (feat_out)
    int k0 = kc * 32 + (lane >> 4) * 8;            // A col base (feat_in)
    const float* src = W + m * HID + k0;
    int off = id * 8;
    for (int j = 0; j < 8; ++j) {
        float w = src[j] * sc;
        _Float16 hw = (_Float16)w;
        _Float16 lw = (_Float16)((w - (float)hw) * 4096.f);
        wsHi[off + j] = __builtin_bit_cast(unsigned short, hw);
        wsLo[off + j] = __builtin_bit_cast(unsigned short, lw);
    }
}

__global__ void __launch_bounds__(BT)
__attribute__((amdgpu_waves_per_eu(3)))
siren_mfma(const float* __restrict__ x,
           const float* __restrict__ w0p, const float* __restrict__ b0p,
           const float* __restrict__ b1p, const float* __restrict__ b2p,
           const float* __restrict__ wfp, const float* __restrict__ bfp,
           const u4v* __restrict__ whi, const u4v* __restrict__ wlo,
           float* __restrict__ out, int NP)
{
    __shared__ unsigned short PHI[PPW * RSTR];     // hi fp16 plane, 4352 B
    __shared__ unsigned short PLO[PPW * RSTR];     // lo fp16 plane, 4352 B

    const int lane = threadIdx.x & 63;
    const int ln = lane & 15, q = lane >> 4;
    const int q4 = q * 4, q8 = q * 8;
    const int base_pt = blockIdx.x * PPW;

    // ---- first SineLayer (fp32 VALU) ----
    // H_{mt}_{reg} = h[point = ln][feat = 16*mt+q4+reg]
    float X, Y, Z;
    { int p_ = base_pt + ln; int ix_ = p_ < NP ? p_ : NP - 1;
      X = x[3*ix_+0]; Y = x[3*ix_+1]; Z = x[3*ix_+2]; }
#define FL0(mt,reg) float H_##mt##_##reg; \
    { const int f_ = mt*16 + q4 + reg; \
      H_##mt##_##reg = sin_om(fmaf(w0p[3*f_+0], X, \
        fmaf(w0p[3*f_+1], Y, fmaf(w0p[3*f_+2], Z, b0p[f_])))); }
    LF32(FL0)

    // activation B-fragments (hi/lo) per kc chunk
    h8v BH0, BH1, BH2, BH3, BL0, BL1, BL2, BL3;

    // h regs -> planes [point][feat]: 4 contiguous feats -> b64 per plane
#define WH(mt, e0,e1,e2,e3) { f4v v_ = {e0, e1, e2, e3}; \
    plane_store4(PHI, PLO, ln*RSTR + mt*16 + q4, v_); }

    // B-frags: b128 per plane
#define RF(kc) { const int a_ = ln*RSTR + kc*32 + q8; \
    BH##kc = *(const h8v*)&PHI[a_]; \
    BL##kc = *(const h8v*)&PLO[a_]; }
#define RF4 RF(0) RF(1) RF(2) RF(3)

    // 3-term split product for one kc chunk into main + lo accumulators
#define KCH(kc, g_, r_) { \
    h8v ah = __builtin_bit_cast(h8v, g_), al = __builtin_bit_cast(h8v, r_); \
    cm = mfmaf(ah, BH##kc, cm); \
    cl = mfmaf(ah, BL##kc, cl); cl = mfmaf(al, BH##kc, cl); }

    // matmul1 (transposed): S1^T = W1 * h^T; sine; store to planes
#define MM1(mt) { \
    const int fb = (L1*32 + mt*4)*64 + lane; \
    u4v g0 = whi[fb], g1 = whi[fb+64], g2 = whi[fb+128], g3 = whi[fb+192]; \
    u4v r0 = wlo[fb], r1 = wlo[fb+64], r2 = wlo[fb+128], r3 = wlo[fb+192]; \
    f4v cm = (*(const f4v*)(B1l + mt*16 + q4)) * 256.0f; \
    f4v cl = {0.f, 0.f, 0.f, 0.f}; \
    KCH(0, g0, r0) KCH(1, g1, r1) KCH(2, g2, r2) KCH(3, g3, r3) \
    f4v z_ = cm + cl * KIN; \
    f4v s_ = {sin_q(z_.x), sin_q(z_.y), sin_q(z_.z), sin_q(z_.w)}; \
    plane_store4(PHI, PLO, ln*RSTR + mt*16 + q4, s_); }

    // matmul2 (transposed) + epilogue h = wgt2*(h + sin(s2))
#define ST5(mt, e0,e1,e2,e3) { \
    const int fb = (L2*32 + mt*4)*64 + lane; \
    u4v g0 = whi[fb], g1 = whi[fb+64], g2 = whi[fb+128], g3 = whi[fb+192]; \
    u4v r0 = wlo[fb], r1 = wlo[fb+64], r2 = wlo[fb+128], r3 = wlo[fb+192]; \
    f4v cm = (*(const f4v*)(B2l + mt*16 + q4)) * 256.0f; \
    f4v cl = {0.f, 0.f, 0.f, 0.f}; \
    KCH(0, g0, r0) KCH(1, g1, r1) KCH(2, g2, r2) KCH(3, g3, r3) \
    f4v z_ = cm + cl * KIN; \
    e0 = wgt2 * (e0 + sin_q(z_.x)); \
    e1 = wgt2 * (e1 + sin_q(z_.y)); \
    e2 = wgt2 * (e2 + sin_q(z_.z)); \
    e3 = wgt2 * (e3 + sin_q(z_.w)); }

    for (int i = 0; i < NRES; ++i) {
        const int L1 = 2 * i, L2 = 2 * i + 1;
        const float* __restrict__ B1l = b1p + i * HID;
        const float* __restrict__ B2l = b2p + i * HID;
        const float wgt2 = (i == NRES - 1) ? 0.5f : 1.0f;   // ave_second

        LT8X(WH)        // h regs -> planes (b64 stores)
        RF4             // h B-fragments
        LMT8(MM1)       // matmul1 + sine -> planes
        RF4             // s1 B-fragments
        LT8X(ST5)       // matmul2 + sine + residual epilogue
    }

    // ---- final linear head: out[p] = bf + sum_f wf[f] h[p][f] ----
#define WFV(mt) f4v WF##mt = *(const f4v*)(wfp + mt*16 + q4);
    LMT8(WFV)
    float P = 0.f;
#define HACC(mt,reg) P = fmaf(WF##mt[reg], H_##mt##_##reg, P);
    LF32(HACC)
    P += __shfl_xor(P, 16);
    P += __shfl_xor(P, 32);
    if (q == 0) {
        int p_ = base_pt + ln;
        if (p_ < NP) out[p_] = P + bfp[0];
    }
}

extern "C" void kernel_launch(void* const* d_in, const int* in_sizes, int n_in,
                              void* d_out, int out_size, void* d_ws, size_t ws_size,
                              hipStream_t stream) {
    const float* x   = (const float*)d_in[0];
    const float* w0  = (const float*)d_in[1];
    const float* b0  = (const float*)d_in[2];
    const float* rw1 = (const float*)d_in[3];
    const float* rb1 = (const float*)d_in[4];
    const float* rw2 = (const float*)d_in[5];
    const float* rb2 = (const float*)d_in[6];
    const float* wf  = (const float*)d_in[7];
    const float* bf  = (const float*)d_in[8];
    float* out = (float*)d_out;

    unsigned short* wsHi = (unsigned short*)d_ws;          // needs 917504 B
    unsigned short* wsLo = wsHi + FRAG_ELEMS;

    const int n = in_sizes[0] / 3;                          // 200000
    prep_kernel<<<112, 256, 0, stream>>>(rw1, rw2, wsHi, wsLo);
    const int grid = (n + PPW - 1) / PPW;                   // 12500 waves
    siren_mfma<<<grid, BT, 0, stream>>>(x, w0, b0, rb1, rb2, wf, bf,
                                        (const u4v*)wsHi, (const u4v*)wsLo,
                                        out, n);
}